// Round 8
// baseline (131.793 us; speedup 1.0000x reference)
//
#include <hip/hip_runtime.h>

// ---------------------------------------------------------------------------
// UniversalBlockEncoder: algebraically folded attention pooling.
//
//   u_i = silu(W1 x_i + b1)                 (the only per-point nonlinearity)
//   s_h(i) = g_h . u_i + d_h    with g_h = W2^T (scale Wk_h^T q_h)
//   p = exp(s)  (scores O(3), f32-safe without max-subtraction)
//   T_h = sum_i p_h(i) u_i ,  l_h = sum_i p_h(i)
//   out = Wo ( Wv ( W2 (T/l) + b2 ) + bv ) + bo
//
// R8: R7 + 2-group ILP: each wave runs TWO independent 64-pt groups through
//     the j-loop at once (two dependency chains; constants amortized; LDS
//     barriers halved). The two points per j pack into one ds_write_b32 via
//     v_perm_b32; k-order is pt-interleaved (k = 2*lane + g) consistently
//     for u and p, so the MFMA contraction (sum over k) is unchanged.
// ---------------------------------------------------------------------------

#define LOG2E 1.44269504088896340736f
#define NLN2  (-0.69314718055994530942f)

#if __has_builtin(__builtin_amdgcn_exp2f)
#define EXP2(x) __builtin_amdgcn_exp2f(x)
#else
#define EXP2(x) exp2f(x)
#endif
#if __has_builtin(__builtin_amdgcn_rcpf)
#define RCP(x) __builtin_amdgcn_rcpf(x)
#else
#define RCP(x) (1.0f / (x))
#endif

// LDS-only ordering within a wave (each wave touches only its own region;
// wave lockstep => lgkmcnt(0) is a sufficient producer-consumer barrier).
#define LDS_WAIT() asm volatile("s_waitcnt lgkmcnt(0)" ::: "memory")

typedef __attribute__((ext_vector_type(8))) __bf16 bf16x8;
typedef __attribute__((ext_vector_type(4))) float  f32x4;

// workspace float offsets
#define WS_C4   0      // 64 x float4 : {-log2e*W1[j][0], -log2e*W1[j][1], -log2e*b1[j], 0}
#define WS_G4   256    // 64 x float4 : -g_h[j]   (NLN2*LOG2E = -1 fold)
#define WS_D    512    // 4           : log2e * d_h
#define WS_ACC  768    // NSLOT x SLOTSTRIDE: [0..3]=l_h, [4+h*64+j]=T'_h[j]
#define NSLOT      16
#define SLOTSTRIDE 272

#define NPTS       (1024 * 1024)
#define K1_BLOCKS  2048
#define K1_THREADS 128
#define WAVES_TOTAL (K1_BLOCKS * 2)                   // 4096
#define GROUPS_PER_WAVE ((NPTS / 64) / WAVES_TOTAL)   // 4
#define PAIR_ITERS (GROUPS_PER_WAVE / 2)              // 2

// per-wave LDS region (shorts), row stride 136 (=272B: 16B-aligned rows,
// dword-bank pattern (4j+lane)%32 -> 2-way = free):
//   p: [h][k]  4 x 136     (rows h>=4 of B-frags alias into u = garbage cols)
//   u: [j][k] 64 x 136     k = 2*lane + g  (pt-interleaved pair order)
#define ROWS 136
#define PW_SHORTS  (4 * ROWS)                 // 544
#define UW_SHORTS  (64 * ROWS)                // 8704
#define WAVE_SHORTS (PW_SHORTS + UW_SHORTS)   // 9248 shorts = 18496 B

// pack hi16(b)|hi16(a)<<16 after round-half-up: dst = {rnd_bf16(a1):rnd_bf16(a0)}
__device__ __forceinline__ unsigned int pack_bf16(float a0, float a1) {
    const unsigned int r0 = __float_as_uint(a0) + 0x8000u;
    const unsigned int r1 = __float_as_uint(a1) + 0x8000u;
    // v_perm_b32: dst.byte[i] = sel.byte[i] of {S0=r1 (bytes 4..7), S1=r0 (bytes 0..3)}
    return __builtin_amdgcn_perm(r1, r0, 0x07060302u);
}

// ---------------------------------------------------------------------------
// Setup: 64 blocks x 64 threads (unchanged from R7).
__global__ void setup_kernel(const float* __restrict__ W1, const float* __restrict__ b1,
                             const float* __restrict__ W2, const float* __restrict__ b2,
                             const float* __restrict__ query,
                             const float* __restrict__ ipw, const float* __restrict__ ipb,
                             float* __restrict__ ws)
{
    __shared__ float qv[64], qs[64], as4[4][64];
    const int t = threadIdx.x;
    const int b = blockIdx.x;     // = output j

    for (int i = b * 64 + t; i < NSLOT * SLOTSTRIDE; i += 64 * 64)
        ws[WS_ACC + i] = 0.0f;

    qv[t] = query[t];
    __syncthreads();

    {
        float a = ipb[t];
        #pragma unroll
        for (int k = 0; k < 64; ++k) a = fmaf(ipw[t * 64 + k], qv[k], a);
        qs[t] = a;
    }
    __syncthreads();

    #pragma unroll
    for (int h = 0; h < 4; ++h) {
        float a = 0.0f;
        #pragma unroll
        for (int m = 0; m < 16; ++m)
            a = fmaf(ipw[(64 + h * 16 + m) * 64 + t], qs[h * 16 + m], a);
        as4[h][t] = 0.25f * a;
    }
    __syncthreads();

    const float w2 = W2[t * 64 + b];
    float g[4];
    #pragma unroll
    for (int h = 0; h < 4; ++h) {
        float v = as4[h][t] * w2;
        for (int m = 1; m < 64; m <<= 1) v += __shfl_xor(v, m);
        g[h] = v;
    }
    if (t == 0) {
        ws[WS_G4 + b * 4 + 0] = -g[0];    // -g: LOG2E*NLN2 fold
        ws[WS_G4 + b * 4 + 1] = -g[1];
        ws[WS_G4 + b * 4 + 2] = -g[2];
        ws[WS_G4 + b * 4 + 3] = -g[3];
        ws[WS_C4 + b * 4 + 0] = -LOG2E * W1[2 * b];
        ws[WS_C4 + b * 4 + 1] = -LOG2E * W1[2 * b + 1];
        ws[WS_C4 + b * 4 + 2] = -LOG2E * b1[b];
        ws[WS_C4 + b * 4 + 3] = 0.0f;
    }
    if (b == 0 && t < 4) {
        float d = 0.0f;
        #pragma unroll
        for (int c = 0; c < 64; ++c) d += as4[t][c] * b2[c];
        float qb = 0.0f;
        #pragma unroll
        for (int m = 0; m < 16; ++m) qb += qs[t * 16 + m] * ipb[64 + t * 16 + m];
        ws[WS_D + t] = LOG2E * (d + 0.25f * qb);
    }
}

// ---------------------------------------------------------------------------
// Main: 2 independent waves/block; each wave runs 2 groups per pass (2 ILP
// chains), 2 passes total. Phase 2: 16x mfma 16x16x32 per pass (K=128).
__global__ __launch_bounds__(K1_THREADS) void main_kernel(
        const float* __restrict__ rr, const float* __restrict__ ri,
        const float4* __restrict__ c4g, const float4* __restrict__ g4g,
        const float* __restrict__ dvec, float* __restrict__ accb)
{
    __shared__ __align__(16) unsigned short lds[2][WAVE_SHORTS];

    const int t    = threadIdx.x;
    const int lane = t & 63;
    const int w    = t >> 6;
    const int m    = lane & 15;
    const int q    = lane >> 4;

    unsigned short* pw = lds[w];               // p: [h][k]
    unsigned short* uw = lds[w] + PW_SHORTS;   // u: [j][k]
    unsigned int*   pw32 = (unsigned int*)pw;
    unsigned int*   uw32 = (unsigned int*)uw;

    const float d0 = dvec[0], d1 = dvec[1], d2 = dvec[2], d3 = dvec[3];

    const int gwave = blockIdx.x * 2 + w;
    float l0 = 0, l1 = 0, l2 = 0, l3 = 0;
    f32x4 acc[4];
    #pragma unroll
    for (int i = 0; i < 4; ++i) acc[i] = (f32x4){0.f, 0.f, 0.f, 0.f};

    // hoist ALL global loads to kernel entry
    float rv[GROUPS_PER_WAVE], iv[GROUPS_PER_WAVE];
    #pragma unroll
    for (int it = 0; it < GROUPS_PER_WAVE; ++it) {
        const int idx = (gwave + it * WAVES_TOTAL) * 64 + lane;
        rv[it] = rr[idx];
        iv[it] = ri[idx];
    }

    for (int it = 0; it < PAIR_ITERS; ++it) {
        const float rA  = rv[2 * it],     imA = iv[2 * it];       // group g=0
        const float rB  = rv[2 * it + 1], imB = iv[2 * it + 1];   // group g=1

        float sA0 = d0, sA1 = d1, sA2 = d2, sA3 = d3;
        float sB0 = d0, sB1 = d1, sB2 = d2, sB3 = d3;
        #pragma unroll 16
        for (int j = 0; j < 64; ++j) {
            const float4 c  = c4g[j];            // wave-uniform -> s_load, shared by both chains
            const float4 gg = g4g[j];
            // chain A
            const float znA = fmaf(c.x, rA, fmaf(c.y, imA, c.z));
            const float eA  = EXP2(znA);
            const float rcA = RCP(1.0f + eA);
            const float ubA = znA * rcA;         // = u / NLN2
            sA0 = fmaf(gg.x, ubA, sA0);
            sA1 = fmaf(gg.y, ubA, sA1);
            sA2 = fmaf(gg.z, ubA, sA2);
            sA3 = fmaf(gg.w, ubA, sA3);
            // chain B (independent)
            const float znB = fmaf(c.x, rB, fmaf(c.y, imB, c.z));
            const float eB  = EXP2(znB);
            const float rcB = RCP(1.0f + eB);
            const float ubB = znB * rcB;
            sB0 = fmaf(gg.x, ubB, sB0);
            sB1 = fmaf(gg.y, ubB, sB1);
            sB2 = fmaf(gg.z, ubB, sB2);
            sB3 = fmaf(gg.w, ubB, sB3);
            // one packed write: k = 2*lane (A) and 2*lane+1 (B)
            uw32[j * (ROWS / 2) + lane] = pack_bf16(ubA, ubB);
        }
        const float pA0 = EXP2(sA0), pA1 = EXP2(sA1), pA2 = EXP2(sA2), pA3 = EXP2(sA3);
        const float pB0 = EXP2(sB0), pB1 = EXP2(sB1), pB2 = EXP2(sB2), pB3 = EXP2(sB3);
        l0 += pA0 + pB0; l1 += pA1 + pB1; l2 += pA2 + pB2; l3 += pA3 + pB3;
        pw32[0 * (ROWS / 2) + lane] = pack_bf16(pA0, pB0);
        pw32[1 * (ROWS / 2) + lane] = pack_bf16(pA1, pB1);
        pw32[2 * (ROWS / 2) + lane] = pack_bf16(pA2, pB2);
        pw32[3 * (ROWS / 2) + lane] = pack_bf16(pA3, pB3);
        LDS_WAIT();    // writes visible to this wave's reads

        // T += U x P over K=128 (k-order pt-interleaved, same for A and B)
        #pragma unroll
        for (int s = 0; s < 4; ++s) {
            const bf16x8 bfrag = *(const bf16x8*)(pw + m * ROWS + 32 * s + q * 8);
            #pragma unroll
            for (int tt = 0; tt < 4; ++tt) {
                const bf16x8 afrag =
                    *(const bf16x8*)(uw + (16 * tt + m) * ROWS + 32 * s + q * 8);
                acc[tt] = __builtin_amdgcn_mfma_f32_16x16x32_bf16(afrag, bfrag, acc[tt], 0, 0, 0);
            }
        }
        LDS_WAIT();    // reads done before next pass overwrites (WAR)
    }

    // l: lane-local partials -> wave reduce
    for (int mm = 1; mm < 64; mm <<= 1) {
        l0 += __shfl_xor(l0, mm);
        l1 += __shfl_xor(l1, mm);
        l2 += __shfl_xor(l2, mm);
        l3 += __shfl_xor(l3, mm);
    }

    // ---- epilogue: transpose D via LDS -> coalesced atomics (R7-proven) ----
    // D: row = q*4 + reg = j_local, col = m = h (cols 4..15 garbage)
    float* scr = (float*)uw;   // reuse u region
    if (m < 4) {
        #pragma unroll
        for (int tt = 0; tt < 4; ++tt)
            #pragma unroll
            for (int reg = 0; reg < 4; ++reg)
                scr[m * 66 + 16 * tt + 4 * q + reg] = acc[tt][reg];
    }
    LDS_WAIT();
    float Th[4];
    #pragma unroll
    for (int h = 0; h < 4; ++h) Th[h] = scr[h * 66 + lane];

    float* accS = accb + (blockIdx.x & (NSLOT - 1)) * SLOTSTRIDE;
    if (lane == 0) {
        atomicAdd(accS + 0, l0);
        atomicAdd(accS + 1, l1);
        atomicAdd(accS + 2, l2);
        atomicAdd(accS + 3, l3);
    }
    atomicAdd(accS + 4 + 0 * 64 + lane, Th[0]);
    atomicAdd(accS + 4 + 1 * 64 + lane, Th[1]);
    atomicAdd(accS + 4 + 2 * 64 + lane, Th[2]);
    atomicAdd(accS + 4 + 3 * 64 + lane, Th[3]);
}

// ---------------------------------------------------------------------------
__global__ void finish_kernel(const float* __restrict__ W2, const float* __restrict__ b2,
                              const float* __restrict__ ipw, const float* __restrict__ ipb,
                              const float* __restrict__ opw, const float* __restrict__ opb,
                              const float* __restrict__ ws, float* __restrict__ out)
{
    __shared__ float red[260];   // [0..3]=l, [4+h*64+k]=T'
    __shared__ float sb[256];    // S-bar per (h, j)
    __shared__ float pl[64];     // pooled
    const int t = threadIdx.x;

    {
        float a = 0.0f;
        for (int s = 0; s < NSLOT; ++s) a += ws[WS_ACC + s * SLOTSTRIDE + t];
        red[t] = a;
        if (t < 4) {
            float a2 = 0.0f;
            for (int s = 0; s < NSLOT; ++s) a2 += ws[WS_ACC + s * SLOTSTRIDE + 256 + t];
            red[256 + t] = a2;
        }
    }
    __syncthreads();

    // S-bar_h[j] = W2[j][:] . (NLN2 * T'_h / l_h) + b2[j]
    {
        const int h = t >> 6, j = t & 63;
        const float inv = NLN2 / red[h];
        float a = 0.0f;
        #pragma unroll
        for (int k = 0; k < 64; ++k) a += W2[j * 64 + k] * red[4 + h * 64 + k];
        sb[t] = fmaf(inv, a, b2[j]);
    }
    __syncthreads();

    if (t < 64) {
        const int h = t >> 4;
        float a = ipb[128 + t];
        #pragma unroll
        for (int d = 0; d < 64; ++d) a += ipw[(128 + t) * 64 + d] * sb[h * 64 + d];
        pl[t] = a;
    }
    __syncthreads();

    if (t < 64) {
        float a = opb[t];
        #pragma unroll
        for (int p = 0; p < 64; ++p) a += opw[t * 64 + p] * pl[p];
        out[t] = a;
    }
}

// ---------------------------------------------------------------------------
extern "C" void kernel_launch(void* const* d_in, const int* in_sizes, int n_in,
                              void* d_out, int out_size, void* d_ws, size_t ws_size,
                              hipStream_t stream)
{
    const float* rr  = (const float*)d_in[0];   // rho_real
    const float* ri  = (const float*)d_in[1];   // rho_imag
    // d_in[2..5]: l_A, l_B, Z_A, Z_B — unused by the reference
    const float* W1  = (const float*)d_in[6];
    const float* b1  = (const float*)d_in[7];
    const float* W2  = (const float*)d_in[8];
    const float* b2  = (const float*)d_in[9];
    const float* qy  = (const float*)d_in[10];
    const float* ipw = (const float*)d_in[11];
    const float* ipb = (const float*)d_in[12];
    const float* opw = (const float*)d_in[13];
    const float* opb = (const float*)d_in[14];
    float* ws  = (float*)d_ws;
    float* out = (float*)d_out;

    setup_kernel<<<64, 64, 0, stream>>>(W1, b1, W2, b2, qy, ipw, ipb, ws);
    main_kernel<<<K1_BLOCKS, K1_THREADS, 0, stream>>>(
        rr, ri,
        (const float4*)(ws + WS_C4), (const float4*)(ws + WS_G4),
        ws + WS_D, ws + WS_ACC);
    finish_kernel<<<1, 256, 0, stream>>>(W2, b2, ipw, ipb, opw, opb, ws, out);
}